// Round 1
// baseline (466.234 us; speedup 1.0000x reference)
//
#include <hip/hip_runtime.h>

// SSIM loss, fused single-pass: (32,3,512,512) fp32 pred/target, 11x11 avg pools,
// output scalar = 1 - mean(ssim_map).
//
// Structure: one block = one 32x32 output tile of one (n,c) image.
//  1. Stage 42x42 input halo tiles (pred, target) to LDS; OOB -> 0 (pad semantics).
//  2. Vertical 11-sums of {p, t, p*p, t*t, p*t} -> 5 LDS arrays [32][42].
//  3. Horizontal 11-sums + SSIM formula per output pixel (4 px/thread).
//  4. Block reduction (wave shuffle + LDS), atomicAdd(double) into d_ws[0].
//  5. finalize kernel: out = 1 - sum/N.

#define TW 32
#define TH 32
#define HALO 10          // 2 * (11/2)
#define IW (TW + HALO)   // 42
#define IH (TH + HALO)   // 42
#define IMGW 512
#define IMGPIX (IMGW * IMGW)
#define WIN 11
#define NIMG 96          // 32 * 3

__global__ __launch_bounds__(256)
void ssim_partial(const float* __restrict__ pred,
                  const float* __restrict__ target,
                  double* __restrict__ accum) {
    __shared__ float sp[IH * IW];
    __shared__ float st[IH * IW];
    __shared__ float v1[TH * IW];
    __shared__ float v2[TH * IW];
    __shared__ float v3[TH * IW];
    __shared__ float v4[TH * IW];
    __shared__ float v5[TH * IW];
    __shared__ float warp_part[4];

    const int tid = threadIdx.x + threadIdx.y * 32;  // blockDim = (32,8)
    const int bx = blockIdx.x, by = blockIdx.y, img = blockIdx.z;
    const float* __restrict__ p = pred   + (size_t)img * IMGPIX;
    const float* __restrict__ t = target + (size_t)img * IMGPIX;

    // ---- 1. stage input tiles (zero-padded at image borders) ----
    for (int idx = tid; idx < IH * IW; idx += 256) {
        int ly = idx / IW, lx = idx - ly * IW;
        int gy = by * TH - 5 + ly;
        int gx = bx * TW - 5 + lx;
        float pv = 0.0f, tv = 0.0f;
        if ((unsigned)gy < IMGW && (unsigned)gx < IMGW) {
            pv = p[gy * IMGW + gx];
            tv = t[gy * IMGW + gx];
        }
        sp[idx] = pv;
        st[idx] = tv;
    }
    __syncthreads();

    // ---- 2. vertical 11-sums of the 5 quantities ----
    for (int idx = tid; idx < TH * IW; idx += 256) {
        int r = idx / IW, c = idx - r * IW;
        int base = r * IW + c;
        float s1 = 0.f, s2 = 0.f, s3 = 0.f, s4 = 0.f, s5 = 0.f;
#pragma unroll
        for (int dr = 0; dr < WIN; ++dr) {
            float pv = sp[base + dr * IW];
            float tv = st[base + dr * IW];
            s1 += pv;
            s2 += tv;
            s3 += pv * pv;
            s4 += tv * tv;
            s5 += pv * tv;
        }
        v1[idx] = s1; v2[idx] = s2; v3[idx] = s3; v4[idx] = s4; v5[idx] = s5;
    }
    __syncthreads();

    // ---- 3. horizontal 11-sums + SSIM formula ----
    const float inv_w2 = 1.0f / (float)(WIN * WIN);
    const float C1 = 1e-4f;   // 0.01^2
    const float C2 = 9e-4f;   // 0.03^2
    float local = 0.0f;
#pragma unroll
    for (int k = 0; k < 4; ++k) {
        int r = threadIdx.y + k * 8;
        int c = threadIdx.x;
        int base = r * IW + c;
        float s1 = 0.f, s2 = 0.f, s3 = 0.f, s4 = 0.f, s5 = 0.f;
#pragma unroll
        for (int dc = 0; dc < WIN; ++dc) {
            s1 += v1[base + dc];
            s2 += v2[base + dc];
            s3 += v3[base + dc];
            s4 += v4[base + dc];
            s5 += v5[base + dc];
        }
        float mu1 = s1 * inv_w2, mu2 = s2 * inv_w2;
        float e11 = s3 * inv_w2, e22 = s4 * inv_w2, e12 = s5 * inv_w2;
        float mu1sq = mu1 * mu1, mu2sq = mu2 * mu2, mu12 = mu1 * mu2;
        float sig1 = e11 - mu1sq;
        float sig2 = e22 - mu2sq;
        float sig12 = e12 - mu12;
        float num = (2.0f * mu12 + C1) * (2.0f * sig12 + C2);
        float den = (mu1sq + mu2sq + C1) * (sig1 + sig2 + C2);
        local += num / den;
    }

    // ---- 4. block reduction -> one double atomic per block ----
#pragma unroll
    for (int off = 32; off > 0; off >>= 1)
        local += __shfl_down(local, off, 64);
    int lane = tid & 63, wid = tid >> 6;
    if (lane == 0) warp_part[wid] = local;
    __syncthreads();
    if (tid == 0) {
        float s = warp_part[0] + warp_part[1] + warp_part[2] + warp_part[3];
        atomicAdd(accum, (double)s);
    }
}

__global__ void ssim_finalize(const double* __restrict__ accum,
                              float* __restrict__ out) {
    const double n = 25165824.0;  // 32*3*512*512
    out[0] = (float)(1.0 - accum[0] / n);
}

extern "C" void kernel_launch(void* const* d_in, const int* in_sizes, int n_in,
                              void* d_out, int out_size, void* d_ws, size_t ws_size,
                              hipStream_t stream) {
    const float* pred   = (const float*)d_in[0];
    const float* target = (const float*)d_in[1];
    float* out = (float*)d_out;
    double* accum = (double*)d_ws;

    // d_ws is re-poisoned to 0xAA before every launch: zero the accumulator.
    hipMemsetAsync(d_ws, 0, sizeof(double), stream);

    dim3 grid(IMGW / TW, IMGW / TH, NIMG);  // 16 x 16 x 96
    dim3 block(32, 8);
    ssim_partial<<<grid, block, 0, stream>>>(pred, target, accum);
    ssim_finalize<<<1, 1, 0, stream>>>(accum, out);
}

// Round 2
// 348.883 us; speedup vs baseline: 1.3364x; 1.3364x over previous
//
#include <hip/hip_runtime.h>

// SSIM loss, fused: (32,3,512,512) fp32, 11x11 avg pools, out = 1 - mean(ssim_map).
//
// R2 structure: one block = 64x32 output tile of one (n,c) image.
//  Stage B: vertical 11-sums of {p,t,p2,t2,pt} via per-thread sliding window,
//           reading DIRECTLY from global (coalesced across lanes; re-reads hit L1).
//           Results packed in LDS: float4 va=(s1,s2,s3,s4), float vb=s5, stride 75
//           (bank-conflict-free for row-strided b128 reads and contiguous writes).
//  Stage C: horizontal 11-sums via sliding window (run of 8 px/thread: 2 LDS
//           reads/px steady state) + SSIM formula + block reduce -> atomicAdd(double).
//  finalize: out = 1 - sum/N.

#define IMGW 512
#define IMGPIX (IMGW * IMGW)
#define TW 64
#define TH 32
#define VCOLS 74      // TW + 10 halo
#define SV 75         // padded LDS row stride (odd -> conflict-free patterns)
#define NRUNS 4       // TH / RUNLEN
#define RUNLEN 8
#define NIMG 96

__global__ __launch_bounds__(256)
void ssim_partial(const float* __restrict__ pred,
                  const float* __restrict__ target,
                  double* __restrict__ accum)
{
    __shared__ float4 va[TH * SV];   // (sum p, sum t, sum p^2, sum t^2)
    __shared__ float  vb[TH * SV];   // sum p*t
    __shared__ float  wpart[4];

    const int tid = threadIdx.x;
    const int bx = blockIdx.x, by = blockIdx.y, img = blockIdx.z;
    const float* __restrict__ p = pred   + (size_t)img * IMGPIX;
    const float* __restrict__ t = target + (size_t)img * IMGPIX;
    const int gx0 = bx * TW - 5;
    const int gy0 = by * TH;

    // ---- Stage B: vertical 11-sums, sliding window, direct from global ----
    for (int unit = tid; unit < VCOLS * NRUNS; unit += 256) {
        const int c   = unit % VCOLS;
        const int run = unit / VCOLS;
        const int gx  = gx0 + c;
        const bool xok = (unsigned)gx < IMGW;
        const int y0 = run * RUNLEN;
        float s1 = 0.f, s2 = 0.f, s3 = 0.f, s4 = 0.f, s5 = 0.f;
#pragma unroll
        for (int dy = -5; dy <= 5; ++dy) {
            const int gy = gy0 + y0 + dy;
            const bool ok = xok && (unsigned)gy < IMGW;
            const float pv = ok ? p[(size_t)gy * IMGW + gx] : 0.f;
            const float tv = ok ? t[(size_t)gy * IMGW + gx] : 0.f;
            s1 += pv; s2 += tv; s3 += pv * pv; s4 += tv * tv; s5 += pv * tv;
        }
        va[y0 * SV + c] = make_float4(s1, s2, s3, s4);
        vb[y0 * SV + c] = s5;
#pragma unroll
        for (int k = 1; k < RUNLEN; ++k) {
            const int y = y0 + k;
            const int gyn = gy0 + y + 5, gyo = gy0 + y - 6;
            const bool okn = xok && (unsigned)gyn < IMGW;
            const bool oko = xok && (unsigned)gyo < IMGW;
            const float pn = okn ? p[(size_t)gyn * IMGW + gx] : 0.f;
            const float tn = okn ? t[(size_t)gyn * IMGW + gx] : 0.f;
            const float po = oko ? p[(size_t)gyo * IMGW + gx] : 0.f;
            const float to = oko ? t[(size_t)gyo * IMGW + gx] : 0.f;
            s1 += pn - po;
            s2 += tn - to;
            s3 += pn * pn - po * po;
            s4 += tn * tn - to * to;
            s5 += pn * tn - po * to;
            va[y * SV + c] = make_float4(s1, s2, s3, s4);
            vb[y * SV + c] = s5;
        }
    }
    __syncthreads();

    // ---- Stage C: horizontal 11-sums, sliding window + SSIM ----
    const float inv = 1.0f / 121.0f;
    const float C1 = 1e-4f, C2 = 9e-4f;
    const int row = tid & 31;            // lanes 0..31 = rows -> conflict-free strided reads
    const int x0  = (tid >> 5) * RUNLEN; // 8 runs cover 64 output cols
    const int rb  = row * SV;
    float local = 0.f;

    float4 S = {0.f, 0.f, 0.f, 0.f};
    float s5 = 0.f;
#pragma unroll
    for (int k = 0; k < 11; ++k) {
        const float4 v = va[rb + x0 + k];
        S.x += v.x; S.y += v.y; S.z += v.z; S.w += v.w;
        s5 += vb[rb + x0 + k];
    }
#pragma unroll
    for (int k = 0; k < RUNLEN; ++k) {
        if (k > 0) {
            const int x = x0 + k;
            const float4 vn = va[rb + x + 10];
            const float4 vo = va[rb + x - 1];
            S.x += vn.x - vo.x; S.y += vn.y - vo.y;
            S.z += vn.z - vo.z; S.w += vn.w - vo.w;
            s5 += vb[rb + x + 10] - vb[rb + x - 1];
        }
        const float mu1 = S.x * inv, mu2 = S.y * inv;
        const float e11 = S.z * inv, e22 = S.w * inv, e12 = s5 * inv;
        const float mu1sq = mu1 * mu1, mu2sq = mu2 * mu2, mu12 = mu1 * mu2;
        const float num = (2.f * mu12 + C1) * (2.f * (e12 - mu12) + C2);
        const float den = (mu1sq + mu2sq + C1) * ((e11 - mu1sq) + (e22 - mu2sq) + C2);
        local += num / den;
    }

    // ---- block reduce -> one double atomic per block ----
#pragma unroll
    for (int off = 32; off > 0; off >>= 1)
        local += __shfl_down(local, off, 64);
    if ((tid & 63) == 0) wpart[tid >> 6] = local;
    __syncthreads();
    if (tid == 0)
        atomicAdd(accum, (double)(wpart[0] + wpart[1] + wpart[2] + wpart[3]));
}

__global__ void ssim_finalize(const double* __restrict__ accum,
                              float* __restrict__ out) {
    const double n = 25165824.0;  // 32*3*512*512
    out[0] = (float)(1.0 - accum[0] / n);
}

extern "C" void kernel_launch(void* const* d_in, const int* in_sizes, int n_in,
                              void* d_out, int out_size, void* d_ws, size_t ws_size,
                              hipStream_t stream) {
    const float* pred   = (const float*)d_in[0];
    const float* target = (const float*)d_in[1];
    float* out = (float*)d_out;
    double* accum = (double*)d_ws;

    hipMemsetAsync(d_ws, 0, sizeof(double), stream);

    dim3 grid(IMGW / TW, IMGW / TH, NIMG);  // 8 x 16 x 96
    dim3 block(256);
    ssim_partial<<<grid, block, 0, stream>>>(pred, target, accum);
    ssim_finalize<<<1, 1, 0, stream>>>(accum, out);
}

// Round 3
// 317.859 us; speedup vs baseline: 1.4668x; 1.0976x over previous
//
#include <hip/hip_runtime.h>

// SSIM loss, fused: (32,3,512,512) fp32, 11x11 avg pools, out = 1 - mean(ssim_map).
//
// R3 structure: one block = 64x32 output tile.
//  Key identity: den uses sig1+sig2 = (E11+E22) - mu1^2 - mu2^2, so only FOUR
//  box-filtered planes are needed: H = (Sum p, Sum t, Sum p^2+t^2, Sum p*t) -> float4.
//
//  Stage B (horizontal 11-sums): thread = (halo row j in 0..41, 16-col run).
//    Loads 8 aligned float4 per tensor covering [x0-8, x0+24) up front (16
//    independent vector loads, vmcnt-pipelined), slides the 11-window in
//    registers, writes one float4 H per cell. LDS row stride 65 float4s ->
//    write banks spread uniformly (4*65 = 260 = 4 mod 32 -> 8 groups x 8 lanes).
//  Stage C (vertical 11-sums): lane = x (contiguous b128 reads, conflict-free
//    by construction), wave w owns 8 output rows; 10-row running sum S kept in
//    registers (8 retained taps), 1 new b128 tap per output px.
//  Block reduce -> atomicAdd(double); finalize: out = 1 - sum/N.

#define IMGW 512
#define IMGPIX (IMGW * IMGW)
#define TW 64
#define TH 32
#define NROWS 42          // TH + 10 halo
#define SH 65             // LDS row stride in float4
#define NIMG 96

__global__ __launch_bounds__(256, 3)
void ssim_partial(const float* __restrict__ pred,
                  const float* __restrict__ target,
                  double* __restrict__ accum)
{
    __shared__ float4 sH[NROWS * SH];   // 43680 B
    __shared__ float  wpart[4];

    const int tid = threadIdx.x;
    const int bx = blockIdx.x, by = blockIdx.y, img = blockIdx.z;
    const float* __restrict__ p = pred   + (size_t)img * IMGPIX;
    const float* __restrict__ t = target + (size_t)img * IMGPIX;
    const int gy0 = by * TH;

    // ---- Stage B: horizontal 11-sums of 4 planes, sliding in registers ----
    if (tid < NROWS * 4) {
        const int j  = tid >> 2;          // halo row 0..41
        const int xr = tid & 3;           // 16-col run
        const int rv = gy0 - 5 + j;       // image row (may be OOB -> zero row)
        const bool rowok = (unsigned)rv < (unsigned)IMGW;
        const int xbase = bx * TW + xr * 16;

        float fp[32], ft[32];
#pragma unroll
        for (int c = 0; c < 8; ++c) {
            const int gx = xbase - 8 + 4 * c;     // multiple of 4 -> aligned float4
            float4 pv = {0.f, 0.f, 0.f, 0.f};
            float4 tv = {0.f, 0.f, 0.f, 0.f};
            if (rowok && (unsigned)gx < (unsigned)IMGW) {
                const size_t off = (size_t)rv * IMGW + gx;
                pv = *(const float4*)(p + off);
                tv = *(const float4*)(t + off);
            }
            fp[4*c+0] = pv.x; fp[4*c+1] = pv.y; fp[4*c+2] = pv.z; fp[4*c+3] = pv.w;
            ft[4*c+0] = tv.x; ft[4*c+1] = tv.y; ft[4*c+2] = tv.z; ft[4*c+3] = tv.w;
        }
        // output x = xbase+k has window indices i = k+3 .. k+13 (i: x = xbase-8+i)
        float s1 = 0.f, s2 = 0.f, s3 = 0.f, s4 = 0.f;
#pragma unroll
        for (int i = 3; i <= 13; ++i) {
            s1 += fp[i];
            s2 += ft[i];
            s3 += fp[i] * fp[i] + ft[i] * ft[i];
            s4 += fp[i] * ft[i];
        }
        const int lbase = j * SH + xr * 16;
#pragma unroll
        for (int k = 0; k < 16; ++k) {
            if (k > 0) {
                const int a = k + 13, b = k + 2;
                s1 += fp[a] - fp[b];
                s2 += ft[a] - ft[b];
                s3 += (fp[a] * fp[a] + ft[a] * ft[a])
                    - (fp[b] * fp[b] + ft[b] * ft[b]);
                s4 += fp[a] * ft[a] - fp[b] * ft[b];
            }
            sH[lbase + k] = make_float4(s1, s2, s3, s4);
        }
    }
    __syncthreads();

    // ---- Stage C: vertical 11-sums (lane = x), SSIM formula ----
    const float inv = 1.0f / 121.0f;
    const float C1 = 1e-4f, C2 = 9e-4f;
    const int lane = tid & 63;
    const int w    = tid >> 6;
    const int ry0  = w * 8;               // 8 output rows per wave

    float4 r[8];
    float4 S = {0.f, 0.f, 0.f, 0.f};
#pragma unroll
    for (int i = 0; i < 8; ++i) {
        r[i] = sH[(ry0 + i) * SH + lane];
        S.x += r[i].x; S.y += r[i].y; S.z += r[i].z; S.w += r[i].w;
    }
    {
        const float4 a8 = sH[(ry0 + 8) * SH + lane];
        const float4 a9 = sH[(ry0 + 9) * SH + lane];
        S.x += a8.x + a9.x; S.y += a8.y + a9.y;
        S.z += a8.z + a9.z; S.w += a8.w + a9.w;
    }
    float local = 0.f;
#pragma unroll
    for (int k = 0; k < 8; ++k) {
        const float4 nw = sH[(ry0 + 10 + k) * SH + lane];
        const float W1 = S.x + nw.x;      // 11-row window sums
        const float W2 = S.y + nw.y;
        const float W3 = S.z + nw.z;
        const float W4 = S.w + nw.w;
        // advance running 10-row sum
        S.x = W1 - r[k].x; S.y = W2 - r[k].y;
        S.z = W3 - r[k].z; S.w = W4 - r[k].w;

        const float mu1 = W1 * inv, mu2 = W2 * inv;
        const float E3  = W3 * inv, E12 = W4 * inv;
        const float mu11 = mu1 * mu1, mu22 = mu2 * mu2, mu12 = mu1 * mu2;
        const float num = (2.f * mu12 + C1) * (2.f * (E12 - mu12) + C2);
        const float den = (mu11 + mu22 + C1) * ((E3 - mu11 - mu22) + C2);
        local += num / den;
    }

    // ---- block reduce -> one double atomic per block ----
#pragma unroll
    for (int off = 32; off > 0; off >>= 1)
        local += __shfl_down(local, off, 64);
    if ((tid & 63) == 0) wpart[tid >> 6] = local;
    __syncthreads();
    if (tid == 0)
        atomicAdd(accum, (double)(wpart[0] + wpart[1] + wpart[2] + wpart[3]));
}

__global__ void ssim_finalize(const double* __restrict__ accum,
                              float* __restrict__ out) {
    const double n = 25165824.0;  // 32*3*512*512
    out[0] = (float)(1.0 - accum[0] / n);
}

extern "C" void kernel_launch(void* const* d_in, const int* in_sizes, int n_in,
                              void* d_out, int out_size, void* d_ws, size_t ws_size,
                              hipStream_t stream) {
    const float* pred   = (const float*)d_in[0];
    const float* target = (const float*)d_in[1];
    float* out = (float*)d_out;
    double* accum = (double*)d_ws;

    hipMemsetAsync(d_ws, 0, sizeof(double), stream);

    dim3 grid(IMGW / TW, IMGW / TH, NIMG);  // 8 x 16 x 96
    dim3 block(256);
    ssim_partial<<<grid, block, 0, stream>>>(pred, target, accum);
    ssim_finalize<<<1, 1, 0, stream>>>(accum, out);
}